// Round 1
// baseline (580.741 us; speedup 1.0000x reference)
//
#include <hip/hip_runtime.h>

#define EPS_F 0.1f
#define N_ELEM 12288   // C*H*W = 3*64*64
#define SCAN_THREADS 1024
#define SCAN_ITEMS 12  // N_ELEM / SCAN_THREADS

// Kernel 1: compute center/err/cond and inclusive-cumsum row assignment.
// Single block of 1024 threads, 12 contiguous elements per thread.
__global__ __launch_bounds__(SCAN_THREADS) void scan_kernel(
    const float* __restrict__ x,
    float* __restrict__ center,
    float* __restrict__ err,
    int* __restrict__ rows,
    int N)
{
    __shared__ int wave_sums[16];  // 1024 / 64 = 16 waves

    const int t    = threadIdx.x;
    const int lane = t & 63;
    const int wave = t >> 6;
    const int base = t * SCAN_ITEMS;

    float c_[SCAN_ITEMS], e_[SCAN_ITEMS];
    int   cnd[SCAN_ITEMS];

    int local = 0;
    #pragma unroll
    for (int i = 0; i < SCAN_ITEMS; i++) {
        float xv = x[base + i];
        float lo = fmaxf(EPS_F - xv, 0.0f) * 0.5f;
        float hi = fmaxf(xv - (1.0f - EPS_F), 0.0f) * 0.5f;
        c_[i] = xv + lo - hi;
        float ev = EPS_F - lo - hi;
        e_[i] = ev;
        cnd[i] = (ev >= 0.0f) ? 1 : 0;
        local += cnd[i];
    }

    // Wave-level inclusive scan of per-thread counts (width 64).
    int inc = local;
    #pragma unroll
    for (int off = 1; off < 64; off <<= 1) {
        int y = __shfl_up(inc, off, 64);
        if (lane >= off) inc += y;
    }
    if (lane == 63) wave_sums[wave] = inc;
    __syncthreads();

    // Serial scan over the 16 wave totals (trivial cost).
    if (t == 0) {
        int acc = 0;
        #pragma unroll
        for (int w = 0; w < 16; w++) {
            acc += wave_sums[w];
            wave_sums[w] = acc;  // inclusive
        }
    }
    __syncthreads();

    const int wave_off = (wave == 0) ? 0 : wave_sums[wave - 1];
    int run = wave_off + (inc - local);  // exclusive prefix for this thread

    #pragma unroll
    for (int i = 0; i < SCAN_ITEMS; i++) {
        run += cnd[i];
        rows[base + i]   = cnd[i] ? run : (N + 1);  // N+1 => dropped
        center[base + i] = c_[i];
        err[base + i]    = e_[i];
    }
}

// Kernel 2: zero-fill the whole output (harness poisons d_out each launch).
__global__ __launch_bounds__(256) void zero_kernel(float4* __restrict__ out, size_t n4)
{
    size_t i      = (size_t)blockIdx.x * blockDim.x + threadIdx.x;
    size_t stride = (size_t)gridDim.x * blockDim.x;
    const float4 z = make_float4(0.0f, 0.0f, 0.0f, 0.0f);
    for (; i < n4; i += stride) out[i] = z;
}

// Kernel 3: write row 0 (center) and scatter err values.
__global__ __launch_bounds__(256) void scatter_kernel(
    const float* __restrict__ center,
    const float* __restrict__ err,
    const int* __restrict__ rows,
    float* __restrict__ out,
    int N)
{
    int k = blockIdx.x * blockDim.x + threadIdx.x;
    if (k >= N) return;
    out[k] = center[k];  // row 0, coalesced
    int r = rows[k];
    if (r <= N) out[(size_t)r * (size_t)N + (size_t)k] = err[k];
}

extern "C" void kernel_launch(void* const* d_in, const int* in_sizes, int n_in,
                              void* d_out, int out_size, void* d_ws, size_t ws_size,
                              hipStream_t stream)
{
    const float* x = (const float*)d_in[0];
    float* out = (float*)d_out;
    const int N = in_sizes[0];  // 12288

    // Workspace layout: center[N] | err[N] | rows[N]  (3*N*4 = 144 KB)
    float* center = (float*)d_ws;
    float* err    = center + N;
    int*   rows   = (int*)(err + N);

    // 1) scan (independent of fill)
    scan_kernel<<<1, SCAN_THREADS, 0, stream>>>(x, center, err, rows, N);

    // 2) zero-fill 604 MB with float4 stores
    size_t n4 = (size_t)out_size / 4;
    int fill_blocks = 8192;
    zero_kernel<<<fill_blocks, 256, 0, stream>>>((float4*)out, n4);

    // 3) scatter nonzeros (stream order guarantees fill is done)
    int sc_blocks = (N + 255) / 256;
    scatter_kernel<<<sc_blocks, 256, 0, stream>>>(center, err, rows, out, N);
}

// Round 2
// 579.454 us; speedup vs baseline: 1.0022x; 1.0022x over previous
//
#include <hip/hip_runtime.h>

#define EPS_F 0.1f
#define SCAN_THREADS 1024
#define SCAN_ITEMS 12  // N / SCAN_THREADS = 12288 / 1024

// Fused kernel: compute center/err/cond, block-wide inclusive scan for row
// assignment, write row 0 (center) and scatter err values. Runs AFTER the
// memset in stream order. Single block, 1024 threads, 12 elements/thread.
__global__ __launch_bounds__(SCAN_THREADS) void finalize_kernel(
    const float* __restrict__ x,
    float* __restrict__ out,
    int N)
{
    __shared__ int wave_sums[16];  // 1024 / 64 = 16 waves

    const int t    = threadIdx.x;
    const int lane = t & 63;
    const int wave = t >> 6;
    const int base = t * SCAN_ITEMS;

    float c_[SCAN_ITEMS], e_[SCAN_ITEMS];
    int   cnd[SCAN_ITEMS];

    int local = 0;
    #pragma unroll
    for (int i = 0; i < SCAN_ITEMS; i++) {
        float xv = x[base + i];
        float lo = fmaxf(EPS_F - xv, 0.0f) * 0.5f;
        float hi = fmaxf(xv - (1.0f - EPS_F), 0.0f) * 0.5f;
        c_[i] = xv + lo - hi;
        float ev = EPS_F - lo - hi;
        e_[i] = ev;
        cnd[i] = (ev >= 0.0f) ? 1 : 0;
        local += cnd[i];
    }

    // Wave-level inclusive scan of per-thread counts (width 64).
    int inc = local;
    #pragma unroll
    for (int off = 1; off < 64; off <<= 1) {
        int y = __shfl_up(inc, off, 64);
        if (lane >= off) inc += y;
    }
    if (lane == 63) wave_sums[wave] = inc;
    __syncthreads();

    // Serial scan over the 16 wave totals (trivial cost).
    if (t == 0) {
        int acc = 0;
        #pragma unroll
        for (int w = 0; w < 16; w++) {
            acc += wave_sums[w];
            wave_sums[w] = acc;  // inclusive
        }
    }
    __syncthreads();

    const int wave_off = (wave == 0) ? 0 : wave_sums[wave - 1];
    int run = wave_off + (inc - local);  // exclusive prefix for this thread

    #pragma unroll
    for (int i = 0; i < SCAN_ITEMS; i++) {
        const int k = base + i;
        out[k] = c_[i];  // row 0, coalesced across the block
        run += cnd[i];
        if (cnd[i]) {
            // selected element k -> row `run` (1-based inclusive cumsum)
            out[(size_t)run * (size_t)N + (size_t)k] = e_[i];
        }
    }
}

extern "C" void kernel_launch(void* const* d_in, const int* in_sizes, int n_in,
                              void* d_out, int out_size, void* d_ws, size_t ws_size,
                              hipStream_t stream)
{
    const float* x = (const float*)d_in[0];
    float* out = (float*)d_out;
    const int N = in_sizes[0];  // 12288

    // 1) zero-fill the whole 604 MB output via the rocclr fill path
    //    (captures as a graph memset node; hits ~6.3 TB/s)
    hipMemsetAsync(d_out, 0, (size_t)out_size * sizeof(float), stream);

    // 2) fused scan + row-0 + scatter (stream order guarantees fill is done)
    finalize_kernel<<<1, SCAN_THREADS, 0, stream>>>(x, out, N);
}